// Round 4
// baseline (6928.701 us; speedup 1.0000x reference)
//
#include <hip/hip_runtime.h>
#include <hip/hip_bf16.h>

// ---------------------------------------------------------------------------
// DynamiSE: encoder GEMM -> 2x GCNConv (atomic scatter) -> fused dopri5 ODE.
// Round 3 resubmit (rounds 1-3 benches all died on the same unresponsive
// MI355X container before source push; kernel has never executed).
// Correctness-first fp32 pipeline. ODE kernel is fully fused:
// W_ode in LDS, per-thread 4x4 register tile, k1..k6 history in registers.
// ---------------------------------------------------------------------------

__device__ __forceinline__ float fast_tanh(float x) {
    // tanh(x) = 1 - 2/(exp(2x)+1), exp via v_exp_f32 (2^(x*2*log2e))
    float e = __builtin_amdgcn_exp2f(x * 2.8853900817779268f);
    return 1.0f - 2.0f * __builtin_amdgcn_rcpf(e + 1.0f);
}

// ---------------- degree / dinv ----------------

__global__ __launch_bounds__(256) void deg_init_kernel(float* degp, float* degn, int n) {
    int i = blockIdx.x * 256 + threadIdx.x;
    if (i < n) { degp[i] = 1.0f; degn[i] = 1.0f; }  // self-loop contributes 1
}

__global__ __launch_bounds__(256) void deg_count_kernel(const int* __restrict__ pdst,
        const int* __restrict__ ndst, float* degp, float* degn, int nE) {
    int e = blockIdx.x * 256 + threadIdx.x;
    if (e < nE) {
        atomicAdd(&degp[pdst[e]], 1.0f);
        atomicAdd(&degn[ndst[e]], 1.0f);
    }
}

__global__ __launch_bounds__(256) void dinv_kernel(float* degp, float* degn, int n) {
    int i = blockIdx.x * 256 + threadIdx.x;
    if (i < n) { degp[i] = rsqrtf(degp[i]); degn[i] = rsqrtf(degn[i]); }
}

// ---------------- encoder: h = x @ W_enc + b_enc  [n,128]@[128,64] ----------------

__global__ __launch_bounds__(256) void encoder_kernel(const float* __restrict__ x,
        const float* __restrict__ W, const float* __restrict__ b,
        float* __restrict__ h, int n) {
    __shared__ __align__(16) float Ws[128 * 64];
    __shared__ __align__(16) float xs[4 * 128];
    int tid = threadIdx.x;
    for (int i = tid; i < 128 * 64; i += 256) Ws[i] = W[i];
    long row = (long)blockIdx.x * 4;
    for (int i = tid; i < 4 * 128; i += 256) {
        long rr = row + (i >> 7);
        xs[i] = (rr < n) ? x[rr * 128 + (i & 127)] : 0.0f;
    }
    __syncthreads();
    int r = tid >> 6, c = tid & 63;
    float acc = b[c];
    #pragma unroll 8
    for (int k = 0; k < 128; k += 4) {
        float4 xv = *(const float4*)&xs[r * 128 + k];
        acc += xv.x * Ws[(k+0)*64+c] + xv.y * Ws[(k+1)*64+c]
             + xv.z * Ws[(k+2)*64+c] + xv.w * Ws[(k+3)*64+c];
    }
    if (row + r < n) h[(row + r) * 64 + c] = acc;
}

// ---------------- hw' = dinv * (h @ W)  for both graphs ----------------

__global__ __launch_bounds__(256) void hw_kernel(const float* __restrict__ h,
        const float* __restrict__ Wp, const float* __restrict__ Wn,
        const float* __restrict__ dinvp, const float* __restrict__ dinvn,
        float* __restrict__ hwp, float* __restrict__ hwn, int n) {
    __shared__ __align__(16) float Wps[64 * 64];
    __shared__ __align__(16) float Wns[64 * 64];
    __shared__ __align__(16) float hs[4 * 64];
    int tid = threadIdx.x;
    for (int i = tid; i < 64 * 64; i += 256) { Wps[i] = Wp[i]; Wns[i] = Wn[i]; }
    long row = (long)blockIdx.x * 4;
    {
        int i = tid;  // 256 elements, one per thread
        long rr = row + (i >> 6);
        hs[i] = (rr < n) ? h[rr * 64 + (i & 63)] : 0.0f;
    }
    __syncthreads();
    int r = tid >> 6, c = tid & 63;
    float ap = 0.0f, an = 0.0f;
    #pragma unroll 4
    for (int k = 0; k < 64; k += 4) {
        float4 hv = *(const float4*)&hs[r * 64 + k];
        ap += hv.x*Wps[(k+0)*64+c] + hv.y*Wps[(k+1)*64+c] + hv.z*Wps[(k+2)*64+c] + hv.w*Wps[(k+3)*64+c];
        an += hv.x*Wns[(k+0)*64+c] + hv.y*Wns[(k+1)*64+c] + hv.z*Wns[(k+2)*64+c] + hv.w*Wns[(k+3)*64+c];
    }
    if (row + r < n) {
        hwp[(row + r) * 64 + c] = ap * dinvp[row + r];
        hwn[(row + r) * 64 + c] = an * dinvn[row + r];
    }
}

// ---------------- y0 init with self-loop term ----------------

__global__ __launch_bounds__(256) void y0_init_kernel(const float* __restrict__ hwp,
        const float* __restrict__ hwn, float* __restrict__ y0, int n) {
    long idx = (long)blockIdx.x * 256 + threadIdx.x;
    if (idx >= (long)n * 128) return;
    long i = idx >> 7; int c = (int)(idx & 127);
    y0[idx] = (c < 64) ? hwp[i * 64 + c] : hwn[i * 64 + (c - 64)];
}

// ---------------- edge scatter: y0[dst] += hw'[src] (wave per edge) ----------------

__global__ __launch_bounds__(256) void scatter_kernel(const int* __restrict__ src,
        const int* __restrict__ dst, const float* __restrict__ hw,
        float* __restrict__ y0, int colOff, int nE) {
    int wid  = blockIdx.x * 4 + (threadIdx.x >> 6);
    int lane = threadIdx.x & 63;
    if (wid >= nE) return;
    int s = src[wid], d = dst[wid];
    atomicAdd(&y0[(long)d * 128 + colOff + lane], hw[(long)s * 64 + lane]);
}

// ---------------- finalize: y0 = dinv[dst]*sum + bias ----------------

__global__ __launch_bounds__(256) void finalize_kernel(float* __restrict__ y0,
        const float* __restrict__ dinvp, const float* __restrict__ dinvn,
        const float* __restrict__ bp, const float* __restrict__ bn, int n) {
    long idx = (long)blockIdx.x * 256 + threadIdx.x;
    if (idx >= (long)n * 128) return;
    long i = idx >> 7; int c = (int)(idx & 127);
    if (c < 64) y0[idx] = dinvp[i] * y0[idx] + bp[c];
    else        y0[idx] = dinvn[i] * y0[idx] + bn[c - 64];
}

// ---------------- fused dopri5 ODE ----------------
// Block: 512 threads = 64 rows x 128 cols, each thread owns a 4x4 tile.
// LDS: W_ode (64KB) + yi tile (32KB) + bias. k1..k6 history in registers.

#define ACC4(ACC, A) \
    ACC.x += A.x*w0.x + A.y*w1.x + A.z*w2.x + A.w*w3.x; \
    ACC.y += A.x*w0.y + A.y*w1.y + A.z*w2.y + A.w*w3.y; \
    ACC.z += A.x*w0.z + A.y*w1.z + A.z*w2.z + A.w*w3.z; \
    ACC.w += A.x*w0.w + A.y*w1.w + A.z*w2.w + A.w*w3.w;

__device__ __forceinline__ void ode_stage(const float yi[4][4], float kout[4][4],
        float* yis, const float* Ws, const float* bs, int r0, int c0) {
    __syncthreads();  // protect yis from previous stage's readers
    #pragma unroll
    for (int i = 0; i < 4; ++i) {
        float4 v; v.x = yi[i][0]; v.y = yi[i][1]; v.z = yi[i][2]; v.w = yi[i][3];
        *(float4*)&yis[(r0 + i) * 128 + c0] = v;
    }
    __syncthreads();
    float4 bv = *(const float4*)&bs[c0];
    float4 acc0 = bv, acc1 = bv, acc2 = bv, acc3 = bv;
    for (int d = 0; d < 128; d += 4) {
        float4 w0 = *(const float4*)&Ws[(d+0)*128 + c0];
        float4 w1 = *(const float4*)&Ws[(d+1)*128 + c0];
        float4 w2 = *(const float4*)&Ws[(d+2)*128 + c0];
        float4 w3 = *(const float4*)&Ws[(d+3)*128 + c0];
        float4 a;
        a = *(const float4*)&yis[(r0+0)*128 + d]; ACC4(acc0, a);
        a = *(const float4*)&yis[(r0+1)*128 + d]; ACC4(acc1, a);
        a = *(const float4*)&yis[(r0+2)*128 + d]; ACC4(acc2, a);
        a = *(const float4*)&yis[(r0+3)*128 + d]; ACC4(acc3, a);
    }
    kout[0][0]=fast_tanh(acc0.x); kout[0][1]=fast_tanh(acc0.y); kout[0][2]=fast_tanh(acc0.z); kout[0][3]=fast_tanh(acc0.w);
    kout[1][0]=fast_tanh(acc1.x); kout[1][1]=fast_tanh(acc1.y); kout[1][2]=fast_tanh(acc1.z); kout[1][3]=fast_tanh(acc1.w);
    kout[2][0]=fast_tanh(acc2.x); kout[2][1]=fast_tanh(acc2.y); kout[2][2]=fast_tanh(acc2.z); kout[2][3]=fast_tanh(acc2.w);
    kout[3][0]=fast_tanh(acc3.x); kout[3][1]=fast_tanh(acc3.y); kout[3][2]=fast_tanh(acc3.z); kout[3][3]=fast_tanh(acc3.w);
}

__global__ __launch_bounds__(512) void ode_kernel(const float* __restrict__ y0,
        float* __restrict__ out, const float* __restrict__ W,
        const float* __restrict__ bb, const float* __restrict__ tt, int n) {
    __shared__ __align__(16) float Ws[128 * 128];
    __shared__ __align__(16) float yis[64 * 128];
    __shared__ __align__(16) float bs[128];
    int tid = threadIdx.x;
    for (int i = tid; i < 128 * 128; i += 512) Ws[i] = W[i];
    if (tid < 128) bs[tid] = bb[tid];
    float hstep = (tt[1] - tt[0]) * 0.03125f;  // /32 steps
    int tc = tid & 31, tr = tid >> 5;
    int r0 = tr * 4, c0 = tc * 4;
    long grow = (long)blockIdx.x * 64 + r0;

    float y[4][4];
    #pragma unroll
    for (int i = 0; i < 4; ++i) {
        if (grow + i < n) {
            float4 v = *(const float4*)&y0[(grow + i) * 128 + c0];
            y[i][0] = v.x; y[i][1] = v.y; y[i][2] = v.z; y[i][3] = v.w;
        } else {
            y[i][0] = y[i][1] = y[i][2] = y[i][3] = 0.0f;
        }
    }

    float k1[4][4], k2[4][4], k3[4][4], k4[4][4], k5[4][4], k6[4][4], yi[4][4];

    for (int step = 0; step < 32; ++step) {
        // stage 1: k1 = f(y)
        ode_stage(y, k1, yis, Ws, bs, r0, c0);
        // stage 2
        #pragma unroll
        for (int i = 0; i < 4; ++i)
        #pragma unroll
        for (int j = 0; j < 4; ++j)
            yi[i][j] = y[i][j] + hstep * (0.2f * k1[i][j]);
        ode_stage(yi, k2, yis, Ws, bs, r0, c0);
        // stage 3
        #pragma unroll
        for (int i = 0; i < 4; ++i)
        #pragma unroll
        for (int j = 0; j < 4; ++j)
            yi[i][j] = y[i][j] + hstep * (0.075f * k1[i][j] + 0.225f * k2[i][j]);
        ode_stage(yi, k3, yis, Ws, bs, r0, c0);
        // stage 4
        #pragma unroll
        for (int i = 0; i < 4; ++i)
        #pragma unroll
        for (int j = 0; j < 4; ++j)
            yi[i][j] = y[i][j] + hstep * (0.9777777777777777f * k1[i][j]
                                        - 3.7333333333333334f * k2[i][j]
                                        + 3.5555555555555554f * k3[i][j]);
        ode_stage(yi, k4, yis, Ws, bs, r0, c0);
        // stage 5
        #pragma unroll
        for (int i = 0; i < 4; ++i)
        #pragma unroll
        for (int j = 0; j < 4; ++j)
            yi[i][j] = y[i][j] + hstep * (2.9525986892242035f * k1[i][j]
                                        - 11.595793324188385f * k2[i][j]
                                        + 9.822892851699436f  * k3[i][j]
                                        - 0.2908093278463649f * k4[i][j]);
        ode_stage(yi, k5, yis, Ws, bs, r0, c0);
        // stage 6
        #pragma unroll
        for (int i = 0; i < 4; ++i)
        #pragma unroll
        for (int j = 0; j < 4; ++j)
            yi[i][j] = y[i][j] + hstep * (2.8462752525252526f * k1[i][j]
                                        - 10.757575757575758f * k2[i][j]
                                        + 8.906422717743473f  * k3[i][j]
                                        + 0.2784090909090909f * k4[i][j]
                                        - 0.2735313036020583f * k5[i][j]);
        ode_stage(yi, k6, yis, Ws, bs, r0, c0);
        // 5th-order update
        #pragma unroll
        for (int i = 0; i < 4; ++i)
        #pragma unroll
        for (int j = 0; j < 4; ++j)
            y[i][j] += hstep * (0.09114583333333333f * k1[i][j]
                              + 0.44923629829290207f * k3[i][j]
                              + 0.6510416666666666f  * k4[i][j]
                              - 0.322376179245283f   * k5[i][j]
                              + 0.13095238095238096f * k6[i][j]);
    }

    #pragma unroll
    for (int i = 0; i < 4; ++i) {
        if (grow + i < n) {
            float4 v; v.x = y[i][0]; v.y = y[i][1]; v.z = y[i][2]; v.w = y[i][3];
            *(float4*)&out[(grow + i) * 128 + c0] = v;
        }
    }
}

// ---------------------------------------------------------------------------

extern "C" void kernel_launch(void* const* d_in, const int* in_sizes, int n_in,
                              void* d_out, int out_size, void* d_ws, size_t ws_size,
                              hipStream_t stream) {
    const float* x     = (const float*)d_in[0];
    const int*   pei   = (const int*)d_in[1];
    const int*   nei   = (const int*)d_in[2];
    const float* t     = (const float*)d_in[3];
    const float* W_enc = (const float*)d_in[4];
    const float* b_enc = (const float*)d_in[5];
    const float* W_pos = (const float*)d_in[6];
    const float* b_pos = (const float*)d_in[7];
    const float* W_neg = (const float*)d_in[8];
    const float* b_neg = (const float*)d_in[9];
    const float* W_ode = (const float*)d_in[10];
    const float* b_ode = (const float*)d_in[11];

    int n  = in_sizes[0] / 128;   // 50000 nodes
    int nE = in_sizes[1] / 2;     // 800000 edges

    // workspace layout (floats): h[n*64] | y0[n*128] | dinvp[n] | dinvn[n]
    float* ws    = (float*)d_ws;
    float* h     = ws;
    float* y0    = ws + (long)n * 64;
    float* dinvp = y0 + (long)n * 128;
    float* dinvn = dinvp + n;

    // d_out doubles as scratch for hw' (pos half then neg half), overwritten by ODE
    float* hwp = (float*)d_out;
    float* hwn = hwp + (long)n * 64;

    const int* psrc = pei;       const int* pdst = pei + nE;
    const int* nsrc = nei;       const int* ndst = nei + nE;

    int nbN  = (n + 255) / 256;
    int nbE  = (nE + 255) / 256;
    int nbR  = (n + 3) / 4;
    long tot = (long)n * 128;
    int nbT  = (int)((tot + 255) / 256);

    deg_init_kernel <<<nbN, 256, 0, stream>>>(dinvp, dinvn, n);
    deg_count_kernel<<<nbE, 256, 0, stream>>>(pdst, ndst, dinvp, dinvn, nE);
    dinv_kernel     <<<nbN, 256, 0, stream>>>(dinvp, dinvn, n);
    encoder_kernel  <<<nbR, 256, 0, stream>>>(x, W_enc, b_enc, h, n);
    hw_kernel       <<<nbR, 256, 0, stream>>>(h, W_pos, W_neg, dinvp, dinvn, hwp, hwn, n);
    y0_init_kernel  <<<nbT, 256, 0, stream>>>(hwp, hwn, y0, n);
    scatter_kernel  <<<(nE + 3) / 4, 256, 0, stream>>>(psrc, pdst, hwp, y0, 0,  nE);
    scatter_kernel  <<<(nE + 3) / 4, 256, 0, stream>>>(nsrc, ndst, hwn, y0, 64, nE);
    finalize_kernel <<<nbT, 256, 0, stream>>>(y0, dinvp, dinvn, b_pos, b_neg, n);
    ode_kernel      <<<(n + 63) / 64, 512, 0, stream>>>(y0, (float*)d_out, W_ode, b_ode, t, n);
}

// Round 5
// 1648.396 us; speedup vs baseline: 4.2033x; 4.2033x over previous
//
#include <hip/hip_runtime.h>
#include <hip/hip_bf16.h>

// ---------------------------------------------------------------------------
// DynamiSE: encoder GEMM -> 2x GCNConv (atomic scatter) -> fused dopri5 ODE.
// Round 5: ODE kernel moved to bf16 MFMA (mfma_f32_16x16x32_bf16).
//   - swapped-operand GEMM: out^T = Wt * yi^T  (A = W^T tile, B = yi^T tile)
//     -> D layout gives each lane 4 consecutive cols of ONE row: LDS writes
//        are 8x ds_write_b64, B-frag reads are contiguous ds_read_b128.
//   - per-wave private 16-row yi subtile -> NO per-stage __syncthreads.
//   - XOR swizzle byte ^= (row&7)<<4 on Wt and yi tiles (bank-uniform).
//   - fp32 y-state/bias/tanh; k1..k5 history packed bf16 (2/VGPR).
// Front-end (GCN path) unchanged from the passing fp32 round (absmax 2e-3).
// ---------------------------------------------------------------------------

typedef __attribute__((ext_vector_type(8))) short short8v;   // 8 bf16 = 4 VGPR
typedef __attribute__((ext_vector_type(4))) float f32x4;
typedef __attribute__((ext_vector_type(2))) unsigned uint2v;

__device__ __forceinline__ float fast_tanh(float x) {
    float e = __builtin_amdgcn_exp2f(x * 2.8853900817779268f);
    return 1.0f - 2.0f * __builtin_amdgcn_rcpf(e + 1.0f);
}

__device__ __forceinline__ unsigned bf16r(float x) {   // RTNE f32->bf16 bits
    unsigned u = __float_as_uint(x);
    return (u + 0x7fffu + ((u >> 16) & 1u)) >> 16;
}
__device__ __forceinline__ unsigned pack2(float lo, float hi) {
    return bf16r(lo) | (bf16r(hi) << 16);
}
__device__ __forceinline__ float unpk(unsigned u, int hi) {
    return __uint_as_float(hi ? (u & 0xffff0000u) : (u << 16));
}
#define KK(A, N, R) unpk(A[(N)*2 + ((R) >> 1)], (R) & 1)

// ---------------- degree / dinv ----------------

__global__ __launch_bounds__(256) void deg_init_kernel(float* degp, float* degn, int n) {
    int i = blockIdx.x * 256 + threadIdx.x;
    if (i < n) { degp[i] = 1.0f; degn[i] = 1.0f; }
}

__global__ __launch_bounds__(256) void deg_count_kernel(const int* __restrict__ pdst,
        const int* __restrict__ ndst, float* degp, float* degn, int nE) {
    int e = blockIdx.x * 256 + threadIdx.x;
    if (e < nE) {
        atomicAdd(&degp[pdst[e]], 1.0f);
        atomicAdd(&degn[ndst[e]], 1.0f);
    }
}

__global__ __launch_bounds__(256) void dinv_kernel(float* degp, float* degn, int n) {
    int i = blockIdx.x * 256 + threadIdx.x;
    if (i < n) { degp[i] = rsqrtf(degp[i]); degn[i] = rsqrtf(degn[i]); }
}

// ---------------- encoder: h = x @ W_enc + b_enc ----------------

__global__ __launch_bounds__(256) void encoder_kernel(const float* __restrict__ x,
        const float* __restrict__ W, const float* __restrict__ b,
        float* __restrict__ h, int n) {
    __shared__ __align__(16) float Ws[128 * 64];
    __shared__ __align__(16) float xs[4 * 128];
    int tid = threadIdx.x;
    for (int i = tid; i < 128 * 64; i += 256) Ws[i] = W[i];
    long row = (long)blockIdx.x * 4;
    for (int i = tid; i < 4 * 128; i += 256) {
        long rr = row + (i >> 7);
        xs[i] = (rr < n) ? x[rr * 128 + (i & 127)] : 0.0f;
    }
    __syncthreads();
    int r = tid >> 6, c = tid & 63;
    float acc = b[c];
    #pragma unroll 8
    for (int k = 0; k < 128; k += 4) {
        float4 xv = *(const float4*)&xs[r * 128 + k];
        acc += xv.x * Ws[(k+0)*64+c] + xv.y * Ws[(k+1)*64+c]
             + xv.z * Ws[(k+2)*64+c] + xv.w * Ws[(k+3)*64+c];
    }
    if (row + r < n) h[(row + r) * 64 + c] = acc;
}

// ---------------- hw' = dinv * (h @ W) for both graphs ----------------

__global__ __launch_bounds__(256) void hw_kernel(const float* __restrict__ h,
        const float* __restrict__ Wp, const float* __restrict__ Wn,
        const float* __restrict__ dinvp, const float* __restrict__ dinvn,
        float* __restrict__ hwp, float* __restrict__ hwn, int n) {
    __shared__ __align__(16) float Wps[64 * 64];
    __shared__ __align__(16) float Wns[64 * 64];
    __shared__ __align__(16) float hs[4 * 64];
    int tid = threadIdx.x;
    for (int i = tid; i < 64 * 64; i += 256) { Wps[i] = Wp[i]; Wns[i] = Wn[i]; }
    long row = (long)blockIdx.x * 4;
    {
        int i = tid;
        long rr = row + (i >> 6);
        hs[i] = (rr < n) ? h[rr * 64 + (i & 63)] : 0.0f;
    }
    __syncthreads();
    int r = tid >> 6, c = tid & 63;
    float ap = 0.0f, an = 0.0f;
    #pragma unroll 4
    for (int k = 0; k < 64; k += 4) {
        float4 hv = *(const float4*)&hs[r * 64 + k];
        ap += hv.x*Wps[(k+0)*64+c] + hv.y*Wps[(k+1)*64+c] + hv.z*Wps[(k+2)*64+c] + hv.w*Wps[(k+3)*64+c];
        an += hv.x*Wns[(k+0)*64+c] + hv.y*Wns[(k+1)*64+c] + hv.z*Wns[(k+2)*64+c] + hv.w*Wns[(k+3)*64+c];
    }
    if (row + r < n) {
        hwp[(row + r) * 64 + c] = ap * dinvp[row + r];
        hwn[(row + r) * 64 + c] = an * dinvn[row + r];
    }
}

// ---------------- y0 init / scatter / finalize ----------------

__global__ __launch_bounds__(256) void y0_init_kernel(const float* __restrict__ hwp,
        const float* __restrict__ hwn, float* __restrict__ y0, int n) {
    long idx = (long)blockIdx.x * 256 + threadIdx.x;
    if (idx >= (long)n * 128) return;
    long i = idx >> 7; int c = (int)(idx & 127);
    y0[idx] = (c < 64) ? hwp[i * 64 + c] : hwn[i * 64 + (c - 64)];
}

__global__ __launch_bounds__(256) void scatter_kernel(const int* __restrict__ src,
        const int* __restrict__ dst, const float* __restrict__ hw,
        float* __restrict__ y0, int colOff, int nE) {
    int wid  = blockIdx.x * 4 + (threadIdx.x >> 6);
    int lane = threadIdx.x & 63;
    if (wid >= nE) return;
    int s = src[wid], d = dst[wid];
    atomicAdd(&y0[(long)d * 128 + colOff + lane], hw[(long)s * 64 + lane]);
}

__global__ __launch_bounds__(256) void finalize_kernel(float* __restrict__ y0,
        const float* __restrict__ dinvp, const float* __restrict__ dinvn,
        const float* __restrict__ bp, const float* __restrict__ bn, int n) {
    long idx = (long)blockIdx.x * 256 + threadIdx.x;
    if (idx >= (long)n * 128) return;
    long i = idx >> 7; int c = (int)(idx & 127);
    if (c < 64) y0[idx] = dinvp[i] * y0[idx] + bp[c];
    else        y0[idx] = dinvn[i] * y0[idx] + bn[c - 64];
}

// ---------------- fused dopri5 ODE, bf16 MFMA ----------------
// Block: 512 threads = 8 waves; wave w owns rows [w*16, w*16+16) of a
// 128-row tile. Per MFMA (16x16x32, swapped operands):
//   acc[n][r] (lane) = out[row = w*16+(lane&15)][c = n*16 + (lane>>4)*4 + r]
//   A-frag: Wt[n*16 + (lane&15)][kk*32 + (lane>>4)*8 + j]   (ds_read_b128)
//   B-frag: yi[w*16 + (lane&15)][kk*32 + (lane>>4)*8 + j]   (ds_read_b128)
// All LDS rows are 256B, byte offsets XOR-swizzled with (row&7)<<4; since
// rows differ from lane only via lane&15, swz = (lane&7)<<4 is per-lane const.

template <typename F>
__device__ __forceinline__ void ode_stage_m(F yi_f, f32x4 ks[8], const unsigned bpk[16],
        char* yrow, const char* wtb, int l15, int q16, int q8, int swz) {
    #pragma unroll
    for (int n = 0; n < 8; ++n) {
        float v0 = yi_f(n, 0), v1 = yi_f(n, 1), v2 = yi_f(n, 2), v3 = yi_f(n, 3);
        uint2v pk; pk.x = pack2(v0, v1); pk.y = pack2(v2, v3);
        *(uint2v*)(yrow + ((n * 32 + q8) ^ swz)) = pk;
    }
    // wave-local: our lanes' writes -> our lanes' reads; no barrier needed
    asm volatile("s_waitcnt lgkmcnt(0)" ::: "memory");
    short8v b0 = *(const short8v*)(yrow + ((  0 + q16) ^ swz));
    short8v b1 = *(const short8v*)(yrow + (( 64 + q16) ^ swz));
    short8v b2 = *(const short8v*)(yrow + ((128 + q16) ^ swz));
    short8v b3 = *(const short8v*)(yrow + ((192 + q16) ^ swz));
    #pragma unroll
    for (int n = 0; n < 8; ++n) {
        const char* ab = wtb + (n * 16 + l15) * 256;
        f32x4 a;
        a[0] = KK(bpk, n, 0); a[1] = KK(bpk, n, 1);
        a[2] = KK(bpk, n, 2); a[3] = KK(bpk, n, 3);
        a = __builtin_amdgcn_mfma_f32_16x16x32_bf16(*(const short8v*)(ab + ((  0 + q16) ^ swz)), b0, a, 0, 0, 0);
        a = __builtin_amdgcn_mfma_f32_16x16x32_bf16(*(const short8v*)(ab + (( 64 + q16) ^ swz)), b1, a, 0, 0, 0);
        a = __builtin_amdgcn_mfma_f32_16x16x32_bf16(*(const short8v*)(ab + ((128 + q16) ^ swz)), b2, a, 0, 0, 0);
        a = __builtin_amdgcn_mfma_f32_16x16x32_bf16(*(const short8v*)(ab + ((192 + q16) ^ swz)), b3, a, 0, 0, 0);
        ks[n][0] = fast_tanh(a[0]); ks[n][1] = fast_tanh(a[1]);
        ks[n][2] = fast_tanh(a[2]); ks[n][3] = fast_tanh(a[3]);
    }
}

__global__ __launch_bounds__(512, 2) void ode_mfma_kernel(const float* __restrict__ y0,
        float* __restrict__ out, const float* __restrict__ W,
        const float* __restrict__ bb, const float* __restrict__ tt, int nrows) {
    __shared__ __align__(16) unsigned short Wt[16384];   // W^T bf16, swizzled, 32KB
    __shared__ __align__(16) unsigned short yis[16384];  // 128 rows x 128 bf16, 32KB
    int tid  = threadIdx.x;
    int lane = tid & 63, w = tid >> 6;
    int l15 = lane & 15, q = lane >> 4;
    int swz = (lane & 7) << 4, q16 = q * 16, q8 = q * 8;

    // stage W^T (bf16, swizzled): Wt[c][d] = W[d][c]
    for (int i = tid; i < 16384; i += 512) {
        int d = i >> 7, c = i & 127;
        unsigned short hb = (unsigned short)bf16r(W[i]);
        *(unsigned short*)((char*)Wt + c * 256 + ((d * 2) ^ ((c & 7) << 4))) = hb;
    }

    float hstep = (tt[1] - tt[0]) * 0.03125f;

    // bias packed bf16 in D layout: c = n*16 + q*4 + r
    unsigned bpk[16];
    #pragma unroll
    for (int n = 0; n < 8; ++n) {
        f32x4 bv = *(const f32x4*)&bb[n * 16 + q * 4];
        bpk[n * 2]     = pack2(bv[0], bv[1]);
        bpk[n * 2 + 1] = pack2(bv[2], bv[3]);
    }

    long grow = (long)blockIdx.x * 128 + w * 16 + l15;
    bool ok = grow < nrows;

    f32x4 y[8];
    #pragma unroll
    for (int n = 0; n < 8; ++n) {
        if (ok) y[n] = *(const f32x4*)&y0[grow * 128 + n * 16 + q * 4];
        else    y[n] = (f32x4){0.0f, 0.0f, 0.0f, 0.0f};
    }

    __syncthreads();  // Wt ready (only barrier in the kernel)

    char* yrow = (char*)yis + (w * 16 + l15) * 256;
    const char* wtb = (const char*)Wt;

    unsigned kp1[16], kp2[16], kp3[16], kp4[16], kp5[16];
    f32x4 ks[8];

    #pragma unroll 1
    for (int step = 0; step < 32; ++step) {
        // stage 1: k1 = f(y)
        ode_stage_m([&](int n, int r) { return y[n][r]; },
                    ks, bpk, yrow, wtb, l15, q16, q8, swz);
        #pragma unroll
        for (int n = 0; n < 8; ++n) { kp1[n*2] = pack2(ks[n][0], ks[n][1]); kp1[n*2+1] = pack2(ks[n][2], ks[n][3]); }
        // stage 2
        ode_stage_m([&](int n, int r) { return y[n][r] + hstep * (0.2f * KK(kp1, n, r)); },
                    ks, bpk, yrow, wtb, l15, q16, q8, swz);
        #pragma unroll
        for (int n = 0; n < 8; ++n) { kp2[n*2] = pack2(ks[n][0], ks[n][1]); kp2[n*2+1] = pack2(ks[n][2], ks[n][3]); }
        // stage 3
        ode_stage_m([&](int n, int r) { return y[n][r] + hstep * (0.075f * KK(kp1, n, r)
                                                                + 0.225f * KK(kp2, n, r)); },
                    ks, bpk, yrow, wtb, l15, q16, q8, swz);
        #pragma unroll
        for (int n = 0; n < 8; ++n) { kp3[n*2] = pack2(ks[n][0], ks[n][1]); kp3[n*2+1] = pack2(ks[n][2], ks[n][3]); }
        // stage 4
        ode_stage_m([&](int n, int r) { return y[n][r] + hstep * (0.9777777777777777f  * KK(kp1, n, r)
                                                                - 3.7333333333333334f * KK(kp2, n, r)
                                                                + 3.5555555555555554f * KK(kp3, n, r)); },
                    ks, bpk, yrow, wtb, l15, q16, q8, swz);
        #pragma unroll
        for (int n = 0; n < 8; ++n) { kp4[n*2] = pack2(ks[n][0], ks[n][1]); kp4[n*2+1] = pack2(ks[n][2], ks[n][3]); }
        // stage 5
        ode_stage_m([&](int n, int r) { return y[n][r] + hstep * (2.9525986892242035f  * KK(kp1, n, r)
                                                                - 11.595793324188385f * KK(kp2, n, r)
                                                                + 9.822892851699436f  * KK(kp3, n, r)
                                                                - 0.2908093278463649f * KK(kp4, n, r)); },
                    ks, bpk, yrow, wtb, l15, q16, q8, swz);
        #pragma unroll
        for (int n = 0; n < 8; ++n) { kp5[n*2] = pack2(ks[n][0], ks[n][1]); kp5[n*2+1] = pack2(ks[n][2], ks[n][3]); }
        // stage 6
        ode_stage_m([&](int n, int r) { return y[n][r] + hstep * (2.8462752525252526f  * KK(kp1, n, r)
                                                                - 10.757575757575758f * KK(kp2, n, r)
                                                                + 8.906422717743473f  * KK(kp3, n, r)
                                                                + 0.2784090909090909f * KK(kp4, n, r)
                                                                - 0.2735313036020583f * KK(kp5, n, r)); },
                    ks, bpk, yrow, wtb, l15, q16, q8, swz);
        // 5th-order update (ks == k6)
        #pragma unroll
        for (int n = 0; n < 8; ++n)
            #pragma unroll
            for (int r = 0; r < 4; ++r)
                y[n][r] += hstep * (0.09114583333333333f * KK(kp1, n, r)
                                  + 0.44923629829290207f * KK(kp3, n, r)
                                  + 0.6510416666666666f  * KK(kp4, n, r)
                                  - 0.322376179245283f   * KK(kp5, n, r)
                                  + 0.13095238095238096f * ks[n][r]);
    }

    if (ok) {
        #pragma unroll
        for (int n = 0; n < 8; ++n)
            *(f32x4*)&out[grow * 128 + n * 16 + q * 4] = y[n];
    }
}

// ---------------------------------------------------------------------------

extern "C" void kernel_launch(void* const* d_in, const int* in_sizes, int n_in,
                              void* d_out, int out_size, void* d_ws, size_t ws_size,
                              hipStream_t stream) {
    const float* x     = (const float*)d_in[0];
    const int*   pei   = (const int*)d_in[1];
    const int*   nei   = (const int*)d_in[2];
    const float* t     = (const float*)d_in[3];
    const float* W_enc = (const float*)d_in[4];
    const float* b_enc = (const float*)d_in[5];
    const float* W_pos = (const float*)d_in[6];
    const float* b_pos = (const float*)d_in[7];
    const float* W_neg = (const float*)d_in[8];
    const float* b_neg = (const float*)d_in[9];
    const float* W_ode = (const float*)d_in[10];
    const float* b_ode = (const float*)d_in[11];

    int n  = in_sizes[0] / 128;   // 50000 nodes
    int nE = in_sizes[1] / 2;     // 800000 edges

    // workspace layout (floats): h[n*64] | y0[n*128] | dinvp[n] | dinvn[n]
    float* ws    = (float*)d_ws;
    float* h     = ws;
    float* y0    = ws + (long)n * 64;
    float* dinvp = y0 + (long)n * 128;
    float* dinvn = dinvp + n;

    // d_out doubles as scratch for hw' (pos half then neg half), overwritten by ODE
    float* hwp = (float*)d_out;
    float* hwn = hwp + (long)n * 64;

    const int* psrc = pei;       const int* pdst = pei + nE;
    const int* nsrc = nei;       const int* ndst = nei + nE;

    int nbN  = (n + 255) / 256;
    int nbE  = (nE + 255) / 256;
    int nbR  = (n + 3) / 4;
    long tot = (long)n * 128;
    int nbT  = (int)((tot + 255) / 256);

    deg_init_kernel <<<nbN, 256, 0, stream>>>(dinvp, dinvn, n);
    deg_count_kernel<<<nbE, 256, 0, stream>>>(pdst, ndst, dinvp, dinvn, nE);
    dinv_kernel     <<<nbN, 256, 0, stream>>>(dinvp, dinvn, n);
    encoder_kernel  <<<nbR, 256, 0, stream>>>(x, W_enc, b_enc, h, n);
    hw_kernel       <<<nbR, 256, 0, stream>>>(h, W_pos, W_neg, dinvp, dinvn, hwp, hwn, n);
    y0_init_kernel  <<<nbT, 256, 0, stream>>>(hwp, hwn, y0, n);
    scatter_kernel  <<<(nE + 3) / 4, 256, 0, stream>>>(psrc, pdst, hwp, y0, 0,  nE);
    scatter_kernel  <<<(nE + 3) / 4, 256, 0, stream>>>(nsrc, ndst, hwn, y0, 64, nE);
    finalize_kernel <<<nbT, 256, 0, stream>>>(y0, dinvp, dinvn, b_pos, b_neg, n);
    ode_mfma_kernel <<<(n + 127) / 128, 512, 0, stream>>>(y0, (float*)d_out, W_ode, b_ode, t, n);
}